// Round 16
// baseline (314.606 us; speedup 1.0000x reference)
//
#include <hip/hip_runtime.h>
#include <stdint.h>

#define CB 32
#define CT 512
#define CK 256
#define TMID 256
#define SEG 16
#define LDP 264            // padded u_lds row, f16 units (264*2B, 16B-aligned rows)
#define MPD 513            // padded mask row, f32 units
#define SHIFT 5.0f
#define ENS 0.006737946999085467f   // e^-5

typedef _Float16 f16x8 __attribute__((ext_vector_type(8)));
typedef float f32x4 __attribute__((ext_vector_type(4)));

__device__ inline uint32_t pk2(float a, float b) {   // exp + pack to 2xf16
    return __builtin_bit_cast(uint32_t,
        __builtin_amdgcn_cvt_pkrtz(__expf(a), __expf(b)));
}
__device__ inline uint32_t pkr(float a, float b) {   // pack only
    return __builtin_bit_cast(uint32_t, __builtin_amdgcn_cvt_pkrtz(a, b));
}

// Barrier draining LDS only; global prefetches stay in flight.
__device__ inline void lds_barrier() {
    asm volatile("s_waitcnt lgkmcnt(0)\n\ts_barrier" ::: "memory");
}

// E^T as MFMA A-operand. Lane l supplies row (l&15) of M-tile (4w+j),
// k-chunk ko8 = (l>>4)*8. fwd: A[st][k] = exp(trans[k][st]) (strided);
// bwd: A[st][k] = exp(trans[st][k]) (contiguous).
#define MKE_F(kt, j) f16x8 E_##kt##_##j; {                                   \
    const float* tp = trans + (size_t)((kt) * 32 + ko8) * CK + (mrow + (j) * 16); \
    uint4 u_;                                                                \
    u_.x = pk2(tp[0],      tp[CK]);                                          \
    u_.y = pk2(tp[2 * CK], tp[3 * CK]);                                      \
    u_.z = pk2(tp[4 * CK], tp[5 * CK]);                                      \
    u_.w = pk2(tp[6 * CK], tp[7 * CK]);                                      \
    E_##kt##_##j = __builtin_bit_cast(f16x8, u_); }

#define MKE_B(kt, j) f16x8 E_##kt##_##j; {                                   \
    const float* tp = trans + (size_t)(mrow + (j) * 16) * CK + ((kt) * 32 + ko8); \
    uint4 u_;                                                                \
    u_.x = pk2(tp[0], tp[1]);                                                \
    u_.y = pk2(tp[2], tp[3]);                                                \
    u_.z = pk2(tp[4], tp[5]);                                                \
    u_.w = pk2(tp[6], tp[7]);                                                \
    E_##kt##_##j = __builtin_bit_cast(f16x8, u_); }

#define LOADE(MK) \
  MK(0,0) MK(0,1) MK(0,2) MK(0,3)  MK(1,0) MK(1,1) MK(1,2) MK(1,3) \
  MK(2,0) MK(2,1) MK(2,2) MK(2,3)  MK(3,0) MK(3,1) MK(3,2) MK(3,3) \
  MK(4,0) MK(4,1) MK(4,2) MK(4,3)  MK(5,0) MK(5,1) MK(5,2) MK(5,3) \
  MK(6,0) MK(6,1) MK(6,2) MK(6,3)  MK(7,0) MK(7,1) MK(7,2) MK(7,3)

#define MMq(kt)                                                              \
    ac0 = __builtin_amdgcn_mfma_f32_16x16x32_f16(E_##kt##_0, U##kt, ac0, 0, 0, 0); \
    ac1 = __builtin_amdgcn_mfma_f32_16x16x32_f16(E_##kt##_1, U##kt, ac1, 0, 0, 0); \
    ac2 = __builtin_amdgcn_mfma_f32_16x16x32_f16(E_##kt##_2, U##kt, ac2, 0, 0, 0); \
    ac3 = __builtin_amdgcn_mfma_f32_16x16x32_f16(E_##kt##_3, U##kt, ac3, 0, 0, 0);

// B-frags (u-matrix): lane l = chain (l&15), k-chunk ko8 -> contiguous b128.
#define MFMA_ALL(ub)                                                         \
    f16x8 U0 = *(const f16x8*)((ub) + 0   + ko8);                            \
    f16x8 U1 = *(const f16x8*)((ub) + 32  + ko8);                            \
    f16x8 U2 = *(const f16x8*)((ub) + 64  + ko8);                            \
    f16x8 U3 = *(const f16x8*)((ub) + 96  + ko8);                            \
    f16x8 U4 = *(const f16x8*)((ub) + 128 + ko8);                            \
    f16x8 U5 = *(const f16x8*)((ub) + 160 + ko8);                            \
    f16x8 U6 = *(const f16x8*)((ub) + 192 + ko8);                            \
    f16x8 U7 = *(const f16x8*)((ub) + 224 + ko8);                            \
    f32x4 ac0 = {0.f,0.f,0.f,0.f}, ac1 = {0.f,0.f,0.f,0.f};                  \
    f32x4 ac2 = {0.f,0.f,0.f,0.f}, ac3 = {0.f,0.f,0.f,0.f};                  \
    MMq(0) MMq(1) MMq(2) MMq(3) MMq(4) MMq(5) MMq(6) MMq(7)

#define STAGE4(ur, s0, s1, s2, s3) {                                         \
    uint2 v0; v0.x = pkr(s0[0], s0[1]); v0.y = pkr(s0[2], s0[3]);            \
    *(uint2*)((ur) + stb)      = v0;                                         \
    uint2 v1; v1.x = pkr(s1[0], s1[1]); v1.y = pkr(s1[2], s1[3]);            \
    *(uint2*)((ur) + stb + 16) = v1;                                         \
    uint2 v2; v2.x = pkr(s2[0], s2[1]); v2.y = pkr(s2[2], s2[3]);            \
    *(uint2*)((ur) + stb + 32) = v2;                                         \
    uint2 v3; v3.x = pkr(s3[0], s3[1]); v3.y = pkr(s3[2], s3[3]);            \
    *(uint2*)((ur) + stb + 48) = v3; }

#define MAX16(a, b2, c2, d2)                                                 \
    fmaxf(fmaxf(fmaxf(fmaxf(a[0], a[1]), fmaxf(a[2], a[3])),                 \
                fmaxf(fmaxf(b2[0], b2[1]), fmaxf(b2[2], b2[3]))),            \
          fmaxf(fmaxf(fmaxf(c2[0], c2[1]), fmaxf(c2[2], c2[3])),             \
                fmaxf(fmaxf(d2[0], d2[1]), fmaxf(d2[2], d2[3]))))

// 4 blocks x 256 threads (4 waves). Block 0,1: fwd batches 0-15/16-31;
// block 2,3: bwd. 16 chains batched in the MFMA M... column dimension:
// D[state][chain], lane l owns chain c=l&15, states stb+j*16+q (j=0..3,q=0..3).
// E^T resident as 32 A-frags (128 regs). Per block-step = 16 chain-steps.
__global__ __launch_bounds__(256, 1) void crf_main_kernel(
    const float* __restrict__ emissions,    // [B,T,K]
    const int* __restrict__ mask,           // [B,T] (bool -> int32)
    const float* __restrict__ trans,        // [K,K]
    float* __restrict__ ws)
{
    const int tid = threadIdx.x;
    const int w = tid >> 6;
    const int l = tid & 63;
    const int c = l & 15;                    // owned chain
    const int g = l >> 4;
    const int ko8 = g * 8;
    const int mrow = w * 64 + c;             // A-row base (output state dim)
    const int stb = w * 64 + g * 4;          // owned output-state base (+j*16+q)
    const bool isF = (blockIdx.x < 2);
    const int bbase = (isF ? blockIdx.x : blockIdx.x - 2) * SEG;

    __shared__ __align__(16) _Float16 u_lds[2][SEG][LDP];
    __shared__ __align__(16) float gpt[2][SEG][4];
    __shared__ float mask_lds[SEG * MPD];

    for (int idx = tid; idx < SEG * CT; idx += 256) {
        const int cc = idx >> 9, tt = idx & (CT - 1);
        mask_lds[cc * MPD + tt] = mask[(bbase + cc) * CT + tt] ? 1.f : 0.f;
    }

    const float* em0 = emissions + (size_t)(bbase + c) * CT * CK + stb;

    float Mref = SHIFT;
    f32x4 uo0, uo1, uo2, uo3;
    float4 ep0, ep1, ep2, ep3;

    if (isF) {
        // ======================= FORWARD =======================
        LOADE(MKE_F)
        ep0 = *(const float4*)(em0 + 0);
        ep1 = *(const float4*)(em0 + 16);
        ep2 = *(const float4*)(em0 + 32);
        ep3 = *(const float4*)(em0 + 48);
        uo0 = (f32x4){__expf(ep0.x-SHIFT), __expf(ep0.y-SHIFT), __expf(ep0.z-SHIFT), __expf(ep0.w-SHIFT)};
        uo1 = (f32x4){__expf(ep1.x-SHIFT), __expf(ep1.y-SHIFT), __expf(ep1.z-SHIFT), __expf(ep1.w-SHIFT)};
        uo2 = (f32x4){__expf(ep2.x-SHIFT), __expf(ep2.y-SHIFT), __expf(ep2.z-SHIFT), __expf(ep2.w-SHIFT)};
        uo3 = (f32x4){__expf(ep3.x-SHIFT), __expf(ep3.y-SHIFT), __expf(ep3.z-SHIFT), __expf(ep3.w-SHIFT)};
        ep0 = *(const float4*)(em0 + CK + 0);
        ep1 = *(const float4*)(em0 + CK + 16);
        ep2 = *(const float4*)(em0 + CK + 32);
        ep3 = *(const float4*)(em0 + CK + 48);
        __syncthreads();   // mask_lds ready

        for (int t = 1; t < TMID; ++t) {
            const int par = t & 1;
            // PRE: stage u (f16) + per-(wave,chain) max
            float pm = MAX16(uo0, uo1, uo2, uo3);
            pm = fmaxf(pm, __shfl_xor(pm, 16, 64));
            pm = fmaxf(pm, __shfl_xor(pm, 32, 64));
            _Float16* ur = u_lds[par][c];
            STAGE4(ur, uo0, uo1, uo2, uo3)
            if (l < 16) gpt[par][l][w] = pm;
            lds_barrier();

            // POST: per-chain scale + MFMA + update
            const float4 gp = *(const float4*)&gpt[par][c][0];
            const float G = fmaxf(fmaxf(gp.x, gp.y), fmaxf(gp.z, gp.w));
            const float fD = __builtin_amdgcn_rcpf(G) * ENS;
            Mref += __logf(G) + SHIFT;
            const _Float16* ub = u_lds[par][c];
            MFMA_ALL(ub)
            const float mv = mask_lds[c * MPD + t];
            const f32x4 ee0 = {__expf(ep0.x), __expf(ep0.y), __expf(ep0.z), __expf(ep0.w)};
            const f32x4 ee1 = {__expf(ep1.x), __expf(ep1.y), __expf(ep1.z), __expf(ep1.w)};
            const f32x4 ee2 = {__expf(ep2.x), __expf(ep2.y), __expf(ep2.z), __expf(ep2.w)};
            const f32x4 ee3 = {__expf(ep3.x), __expf(ep3.y), __expf(ep3.z), __expf(ep3.w)};
            const size_t nt = (size_t)((t + 1 < TMID) ? t + 1 : TMID - 1) * CK;
            ep0 = *(const float4*)(em0 + nt + 0);
            ep1 = *(const float4*)(em0 + nt + 16);
            ep2 = *(const float4*)(em0 + nt + 32);
            ep3 = *(const float4*)(em0 + nt + 48);
            const bool mk = (mv != 0.f);
            uo0 = fD * (mk ? ac0 * ee0 : uo0);
            uo1 = fD * (mk ? ac1 * ee1 : uo1);
            uo2 = fD * (mk ? ac2 * ee2 : uo2);
            uo3 = fD * (mk ? ac3 * ee3 : uo3);
        }
        float* wp = ws + 2 * CB + (size_t)(bbase + c) * CK + stb;
        wp[0]  = Mref + __logf(uo0[0]); wp[1]  = Mref + __logf(uo0[1]);
        wp[2]  = Mref + __logf(uo0[2]); wp[3]  = Mref + __logf(uo0[3]);
        wp[16] = Mref + __logf(uo1[0]); wp[17] = Mref + __logf(uo1[1]);
        wp[18] = Mref + __logf(uo1[2]); wp[19] = Mref + __logf(uo1[3]);
        wp[32] = Mref + __logf(uo2[0]); wp[33] = Mref + __logf(uo2[1]);
        wp[34] = Mref + __logf(uo2[2]); wp[35] = Mref + __logf(uo2[3]);
        wp[48] = Mref + __logf(uo3[0]); wp[49] = Mref + __logf(uo3[1]);
        wp[50] = Mref + __logf(uo3[2]); wp[51] = Mref + __logf(uo3[3]);
    } else {
        // ======================= BACKWARD =======================
        LOADE(MKE_B)
        const float u0i = __expf(-SHIFT);
        uo0 = (f32x4){u0i, u0i, u0i, u0i};
        uo1 = uo0; uo2 = uo0; uo3 = uo0;
        {
            const size_t o = (size_t)(CT - 1) * CK;
            ep0 = *(const float4*)(em0 + o + 0);
            ep1 = *(const float4*)(em0 + o + 16);
            ep2 = *(const float4*)(em0 + o + 32);
            ep3 = *(const float4*)(em0 + o + 48);
        }
        __syncthreads();   // mask_lds ready

        for (int tn = CT - 1; tn >= TMID; --tn) {
            const int par = tn & 1;
            // PRE: stage q = u * exp(emit[tn])
            const f32x4 ee0 = {__expf(ep0.x), __expf(ep0.y), __expf(ep0.z), __expf(ep0.w)};
            const f32x4 ee1 = {__expf(ep1.x), __expf(ep1.y), __expf(ep1.z), __expf(ep1.w)};
            const f32x4 ee2 = {__expf(ep2.x), __expf(ep2.y), __expf(ep2.z), __expf(ep2.w)};
            const f32x4 ee3 = {__expf(ep3.x), __expf(ep3.y), __expf(ep3.z), __expf(ep3.w)};
            const f32x4 s0 = uo0 * ee0, s1 = uo1 * ee1, s2 = uo2 * ee2, s3 = uo3 * ee3;
            float pm = MAX16(s0, s1, s2, s3);
            pm = fmaxf(pm, __shfl_xor(pm, 16, 64));
            pm = fmaxf(pm, __shfl_xor(pm, 32, 64));
            _Float16* ur = u_lds[par][c];
            STAGE4(ur, s0, s1, s2, s3)
            if (l < 16) gpt[par][l][w] = pm;
            lds_barrier();

            // POST
            const float4 gp = *(const float4*)&gpt[par][c][0];
            const float G = fmaxf(fmaxf(gp.x, gp.y), fmaxf(gp.z, gp.w));
            const float fD = __builtin_amdgcn_rcpf(G) * ENS;
            Mref += __logf(G) + SHIFT;
            const _Float16* ub = u_lds[par][c];
            MFMA_ALL(ub)
            const float mv = mask_lds[c * MPD + tn];
            const size_t nt = (size_t)((tn - 1 > TMID) ? tn - 1 : TMID) * CK;
            ep0 = *(const float4*)(em0 + nt + 0);
            ep1 = *(const float4*)(em0 + nt + 16);
            ep2 = *(const float4*)(em0 + nt + 32);
            ep3 = *(const float4*)(em0 + nt + 48);
            const bool mk = (mv != 0.f);
            uo0 = fD * (mk ? ac0 : uo0);
            uo1 = fD * (mk ? ac1 : uo1);
            uo2 = fD * (mk ? ac2 : uo2);
            uo3 = fD * (mk ? ac3 : uo3);
        }
        float* wp = ws + 2 * CB + CB * CK + (size_t)(bbase + c) * CK + stb;
        wp[0]  = Mref + __logf(uo0[0]); wp[1]  = Mref + __logf(uo0[1]);
        wp[2]  = Mref + __logf(uo0[2]); wp[3]  = Mref + __logf(uo0[3]);
        wp[16] = Mref + __logf(uo1[0]); wp[17] = Mref + __logf(uo1[1]);
        wp[18] = Mref + __logf(uo1[2]); wp[19] = Mref + __logf(uo1[3]);
        wp[32] = Mref + __logf(uo2[0]); wp[33] = Mref + __logf(uo2[1]);
        wp[34] = Mref + __logf(uo2[2]); wp[35] = Mref + __logf(uo2[3]);
        wp[48] = Mref + __logf(uo3[0]); wp[49] = Mref + __logf(uo3[1]);
        wp[50] = Mref + __logf(uo3[2]); wp[51] = Mref + __logf(uo3[3]);
    }
}

// Numerator + logZ_b = LSE_j(alpha_mid + beta_mid)
__global__ void crf_combine_kernel(const float* __restrict__ emissions,
                                   const int* __restrict__ tags,
                                   const int* __restrict__ mask,
                                   const float* __restrict__ trans,
                                   float* __restrict__ ws) {
    const int b = blockIdx.x;
    const int tid = threadIdx.x;                 // 256 threads, 4 waves
    const int wid = tid >> 6, lane = tid & 63;
    __shared__ float red[8];
    const float* emB = emissions + (size_t)b * CT * CK;
    const int* tagB = tags + b * CT;
    const int* maskB = mask + b * CT;

    float num = 0.f;
    for (int t = tid; t < CT; t += 256) {
        const float mf = maskB[t] ? 1.f : 0.f;
        num += emB[(size_t)t * CK + tagB[t]] * mf;
        if (t >= 1) num += trans[(size_t)tagB[t - 1] * CK + tagB[t]] * mf;
    }
    #pragma unroll
    for (int off = 32; off > 0; off >>= 1) num += __shfl_down(num, off, 64);
    if (lane == 0) red[wid] = num;
    __syncthreads();
    if (tid == 0) ws[CB + b] = red[0] + red[1] + red[2] + red[3];
    __syncthreads();

    const float v = ws[2 * CB + b * CK + tid] + ws[2 * CB + CB * CK + b * CK + tid];
    float mx = v;
    #pragma unroll
    for (int off = 32; off > 0; off >>= 1) mx = fmaxf(mx, __shfl_down(mx, off, 64));
    mx = __shfl(mx, 0, 64);
    if (lane == 0) red[wid] = mx;
    __syncthreads();
    const float gmx = fmaxf(fmaxf(red[0], red[1]), fmaxf(red[2], red[3]));
    float ex = __expf(v - gmx);
    #pragma unroll
    for (int off = 32; off > 0; off >>= 1) ex += __shfl_down(ex, off, 64);
    if (lane == 0) red[4 + wid] = ex;
    __syncthreads();
    if (tid == 0) ws[b] = gmx + __logf(red[4] + red[5] + red[6] + red[7]);
}

__global__ void crf_finalize_kernel(const float* __restrict__ ws,
                                    float* __restrict__ out) {
    float v = 0.f;
    if ((int)threadIdx.x < CB) v = ws[threadIdx.x] - ws[CB + threadIdx.x];
    #pragma unroll
    for (int off = 32; off > 0; off >>= 1) v += __shfl_down(v, off, 64);
    if (threadIdx.x == 0) out[0] = v * (1.f / CB);
}

extern "C" void kernel_launch(void* const* d_in, const int* in_sizes, int n_in,
                              void* d_out, int out_size, void* d_ws, size_t ws_size,
                              hipStream_t stream) {
    const float* emissions = (const float*)d_in[0];
    const int* tags = (const int*)d_in[1];
    const int* mask = (const int*)d_in[2];
    const float* trans = (const float*)d_in[3];
    float* out = (float*)d_out;
    float* ws = (float*)d_ws;

    crf_main_kernel<<<4, 256, 0, stream>>>(emissions, mask, trans, ws);
    crf_combine_kernel<<<CB, 256, 0, stream>>>(emissions, tags, mask, trans, ws);
    crf_finalize_kernel<<<1, 64, 0, stream>>>(ws, out);
}